// Round 2
// baseline (412.999 us; speedup 1.0000x reference)
//
#include <hip/hip_runtime.h>
#include <hip/hip_bf16.h>

// ---------------------------------------------------------------------------
// TransformerEncoder forward on MI355X (gfx950). Round 1:
//   - m97-class GEMM: 128x128 tile, BK=32, 4 waves, global_load_lds(16B),
//     pre-swizzled sources for conflict-free ds_read_b128, 2-phase pipeline
//   - fused QKV GEMM (N=6144), batched weight-transpose prep (1 launch)
// ---------------------------------------------------------------------------

typedef __bf16 bf16_t;
typedef __bf16 bf16x8 __attribute__((ext_vector_type(8)));
typedef float  f32x4  __attribute__((ext_vector_type(4)));

#define SEQL 512
#define DM   2048
#define FFH  8192
#define NH   16
#define DHD  128

__device__ __forceinline__ unsigned short bfbits(float f){
  bf16_t h = (bf16_t)f;
  return __builtin_bit_cast(unsigned short, h);
}
__device__ __forceinline__ unsigned int pack2(float a, float b){
  return (unsigned int)bfbits(a) | ((unsigned int)bfbits(b) << 16);
}

__device__ __forceinline__ void gll16(const bf16_t* g, bf16_t* l){
  __builtin_amdgcn_global_load_lds(
      (const __attribute__((address_space(1))) void*)g,
      (__attribute__((address_space(3))) void*)l, 16, 0, 0);
}

// ---------------------------------------------------------------------------
// fp32 -> bf16 elementwise convert (for `sequence`)
__global__ __launch_bounds__(256)
void cvt_bf16(const float* __restrict__ in, bf16_t* __restrict__ out){
  const int i = (blockIdx.x * 256 + threadIdx.x) * 4;
  const float4 v = *(const float4*)(in + i);
  ushort4 o;
  o.x = bfbits(v.x); o.y = bfbits(v.y); o.z = bfbits(v.z); o.w = bfbits(v.w);
  *(ushort4*)(out + i) = o;
}

// ---------------------------------------------------------------------------
// Batched transpose+convert: out[oR][oC] = in[src(oC)][oR] as bf16.
// perm=1 (Wo): src(k') = 16*(k'&127) + (k'>>7).
struct TEnt { const float* src; bf16_t* dst; int inR, inC, tilesX, tileBase, perm; };
struct TArgs { TEnt e[7]; };

__global__ __launch_bounds__(256)
void prep_transpose(TArgs args){
  __shared__ bf16_t t[64*65];
  const int b = blockIdx.x;
  int i = 0;
#pragma unroll
  for (int j = 1; j < 7; ++j) if (b >= args.e[j].tileBase) i = j;
  const TEnt E = args.e[i];
  const int tloc = b - E.tileBase;
  const int tx = tloc % E.tilesX, ty = tloc / E.tilesX;
  const int C0 = tx * 64, R0 = ty * 64;
  const int tid = threadIdx.x;
#pragma unroll
  for (int it = 0; it < 4; ++it){
    const int ii = it*16 + (tid >> 4);
    const int j0 = (tid & 15) * 4;
    const int cc = C0 + ii;
    const int srow = E.perm ? (((cc & 127) << 4) + (cc >> 7)) : cc;
    const float4 v = *(const float4*)(E.src + (size_t)srow * E.inC + R0 + j0);
    t[(j0+0)*65 + ii] = (bf16_t)v.x;
    t[(j0+1)*65 + ii] = (bf16_t)v.y;
    t[(j0+2)*65 + ii] = (bf16_t)v.z;
    t[(j0+3)*65 + ii] = (bf16_t)v.w;
  }
  __syncthreads();
#pragma unroll
  for (int it = 0; it < 2; ++it){
    const int r  = it*32 + (tid >> 3);
    const int c0 = (tid & 7) * 8;
    unsigned short us[8];
#pragma unroll
    for (int u = 0; u < 8; ++u) us[u] = __builtin_bit_cast(unsigned short, t[r*65 + c0 + u]);
    uint4 o;
    o.x = (unsigned)us[0] | ((unsigned)us[1] << 16);
    o.y = (unsigned)us[2] | ((unsigned)us[3] << 16);
    o.z = (unsigned)us[4] | ((unsigned)us[5] << 16);
    o.w = (unsigned)us[6] | ((unsigned)us[7] << 16);
    *(uint4*)(E.dst + (size_t)(R0 + r) * E.inR + C0 + c0) = o;
  }
}

// ---------------------------------------------------------------------------
// GEMM: C[512][N] = A[512][K](bf16) @ BT[N][K]^T + bias, templated epilogue.
// 128x128 tile, BK=32, 256 threads; wave w -> 64x64 sub-tile (wr,wc), 4x4 frags.
// LDS linear [row][32] per buffer; 16B slot s of row r stores data slot
// s ^ ((r>>1)&3)  (pre-swizzled at the global source; reads XOR the same way).
constexpr int E_X    = 0;  // + posenc -> X fp32 + XB bf16
constexpr int E_QKV  = 1;  // cols [0,2048) -> Qf, [2048,4096) -> Kf, rest -> Vt[h][d][key]
constexpr int E_AO   = 2;  // + resid -> fp32
constexpr int E_FFN1 = 3;  // gelu -> bf16 (leading dim FFH)
constexpr int E_FFN2 = 4;  // + resid -> fp32

template<int EPI>
__global__ __launch_bounds__(256, 2)
void gemm128(const bf16_t* __restrict__ A, const bf16_t* __restrict__ BT,
             const float* __restrict__ b0p, const float* __restrict__ b1p,
             const float* __restrict__ b2p, const float* __restrict__ resid,
             float* __restrict__ outF, bf16_t* __restrict__ o0,
             bf16_t* __restrict__ o1, bf16_t* __restrict__ o2,
             int N, int K)
{
  __shared__ bf16_t sA[2][128*32];
  __shared__ bf16_t sB[2][128*32];
  const int tid  = threadIdx.x;
  const int lane = tid & 63, w = tid >> 6;
  const int wr = w >> 1, wc = w & 1;
  const int c = lane & 15, g = lane >> 4;
  const int m0 = blockIdx.y * 128, n0 = blockIdx.x * 128;

  // staging sources (pre-swizzled slot within each 64B row)
  const bf16_t* As[2]; const bf16_t* Bs[2];
#pragma unroll
  for (int i = 0; i < 2; ++i){
    const int ck = i*256 + w*64 + lane;
    const int r = ck >> 2, s = ck & 3;
    const int col = ((s ^ ((r >> 1) & 3)) << 3);
    As[i] = A  + (size_t)(m0 + r) * K + col;
    Bs[i] = BT + (size_t)(n0 + r) * K + col;
  }

  // fragment read offsets (elements into a [128][32] buffer)
  int raA[4], raB[4];
#pragma unroll
  for (int m = 0; m < 4; ++m){
    int r = wr*64 + m*16 + c;
    raA[m] = r*32 + ((g ^ ((r >> 1) & 3)) << 3);
    r = wc*64 + m*16 + c;
    raB[m] = r*32 + ((g ^ ((r >> 1) & 3)) << 3);
  }

#define STAGE(buf, kt) {                                   \
    gll16(As[0] + (kt)*32, &sA[buf][(w*64)*8]);            \
    gll16(As[1] + (kt)*32, &sA[buf][(256 + w*64)*8]);      \
    gll16(Bs[0] + (kt)*32, &sB[buf][(w*64)*8]);            \
    gll16(Bs[1] + (kt)*32, &sB[buf][(256 + w*64)*8]);      }

  f32x4 acc[4][4] = {};
  const int nk = K >> 5;

  STAGE(0, 0);
  asm volatile("s_waitcnt vmcnt(0)" ::: "memory");
  __builtin_amdgcn_s_barrier();
  __builtin_amdgcn_sched_barrier(0);

  int buf = 0;
  for (int kt = 0; kt < nk; ++kt){
    if (kt + 1 < nk) STAGE(buf ^ 1, kt + 1);
    bf16x8 af[4], bq[4];
#pragma unroll
    for (int m = 0; m < 4; ++m) af[m] = *(const bf16x8*)&sA[buf][raA[m]];
#pragma unroll
    for (int n = 0; n < 4; ++n) bq[n] = *(const bf16x8*)&sB[buf][raB[n]];
#pragma unroll
    for (int m = 0; m < 4; ++m)
#pragma unroll
      for (int n = 0; n < 4; ++n)
        acc[m][n] = __builtin_amdgcn_mfma_f32_16x16x32_bf16(af[m], bq[n], acc[m][n], 0,0,0);
    asm volatile("s_waitcnt vmcnt(0)" ::: "memory");
    __builtin_amdgcn_s_barrier();
    __builtin_amdgcn_sched_barrier(0);
    buf ^= 1;
  }
#undef STAGE

  // epilogue: row = m0 + wr*64 + m*16 + 4g + rr, col = n0 + wc*64 + n*16 + c
#pragma unroll
  for (int n = 0; n < 4; ++n){
    const int col = n0 + wc*64 + n*16 + c;
#pragma unroll
    for (int m = 0; m < 4; ++m){
      const int row0 = m0 + wr*64 + m*16 + 4*g;
      const f32x4 a4 = acc[m][n];
      if constexpr (EPI == E_X){
        const float bv = b0p[col];
        const float fr = 1e-4f * __expf(-(float)(col >> 1) * (1.0f/1024.0f));
#pragma unroll
        for (int rr = 0; rr < 4; ++rr){
          const int row = row0 + rr;
          float v = a4[rr] + bv;
          const float ang = (float)row * fr;
          v += (col & 1) ? __cosf(ang) : __sinf(ang);
          outF[(size_t)row*DM + col] = v;
          o0[(size_t)row*DM + col]   = (bf16_t)v;
        }
      } else if constexpr (EPI == E_QKV){
        if (col < DM){
          const float bv = b0p[col];
#pragma unroll
          for (int rr = 0; rr < 4; ++rr)
            o0[(size_t)(row0+rr)*DM + col] = (bf16_t)(a4[rr] + bv);
        } else if (col < 2*DM){
          const int cc = col - DM;
          const float bv = b1p[cc];
#pragma unroll
          for (int rr = 0; rr < 4; ++rr)
            o1[(size_t)(row0+rr)*DM + cc] = (bf16_t)(a4[rr] + bv);
        } else {
          const int cc = col - 2*DM;
          const float bv = b2p[cc];
          const int hh = cc & 15, dd = cc >> 4;
          unsigned short us[4];
#pragma unroll
          for (int rr = 0; rr < 4; ++rr) us[rr] = bfbits(a4[rr] + bv);
          *(ushort4*)&o2[(size_t)(hh*DHD + dd)*SEQL + row0] =
              make_ushort4(us[0], us[1], us[2], us[3]);
        }
      } else if constexpr (EPI == E_AO || EPI == E_FFN2){
        const float bv = b0p[col];
#pragma unroll
        for (int rr = 0; rr < 4; ++rr){
          const int row = row0 + rr;
          outF[(size_t)row*DM + col] = a4[rr] + bv + resid[(size_t)row*DM + col];
        }
      } else if constexpr (EPI == E_FFN1){
        const float bv = b0p[col];
#pragma unroll
        for (int rr = 0; rr < 4; ++rr){
          const float v = a4[rr] + bv;
          const float z = v * (v*v*0.044715f + 1.0f) * 1.5957691216f;
          const float gg = v / (1.0f + __expf(-z));
          o0[(size_t)(row0+rr)*FFH + col] = (bf16_t)gg;
        }
      }
    }
  }
}

// ---------------------------------------------------------------------------
// Gather Q/K flat [row][16d+h] -> head layout [h][row][d]; Q scaled by 1/sqrt(2048)
__global__ __launch_bounds__(256)
void permute_qk(const bf16_t* __restrict__ Qf, const bf16_t* __restrict__ Kf,
                bf16_t* __restrict__ Qhd, bf16_t* __restrict__ Khd)
{
  const int row = blockIdx.x, which = blockIdx.y, tid = threadIdx.x;
  const bf16_t* src = (which ? Kf : Qf) + (size_t)row * DM;
  bf16_t* dst = which ? Khd : Qhd;
  const int hh = tid >> 4, d0 = (tid & 15) * 8;
  const float scale = which ? 1.0f : 0.022097086912079612f;  // 1/sqrt(2048)
  float v[8];
#pragma unroll
  for (int j = 0; j < 8; ++j) v[j] = (float)src[(d0 + j)*NH + hh] * scale;
  uint4 o;
  o.x = pack2(v[0], v[1]); o.y = pack2(v[2], v[3]);
  o.z = pack2(v[4], v[5]); o.w = pack2(v[6], v[7]);
  *(uint4*)&dst[(size_t)hh*(SEQL*DHD) + (size_t)row*DHD + d0] = o;
}

// ---------------------------------------------------------------------------
// Attention: one block per (32 q-rows, head). Full softmax over 512 keys.
__global__ __launch_bounds__(256)
void attn_kernel(const bf16_t* __restrict__ Qh, const bf16_t* __restrict__ Kh,
                 const bf16_t* __restrict__ Vt, bf16_t* __restrict__ Aout)
{
  __shared__ bf16_t Pl[32*512];
  __shared__ float redm[4][32];
  __shared__ float reds[4][32];
  const int tid = threadIdx.x;
  const int lane = tid & 63, w = tid >> 6;
  const int c = lane & 15, g = lane >> 4;
  const int h = blockIdx.y;
  const int rb = blockIdx.x * 32;
  const bf16_t* Qb = Qh + (size_t)h * (SEQL*DHD);
  const bf16_t* Kb = Kh + (size_t)h * (SEQL*DHD);
  const bf16_t* Vb = Vt + (size_t)h * (SEQL*DHD);

  bf16x8 qf[2][4];
#pragma unroll
  for (int a = 0; a < 2; ++a)
#pragma unroll
    for (int ks = 0; ks < 4; ++ks)
      qf[a][ks] = *(const bf16x8*)(Qb + (size_t)(rb + a*16 + c)*DHD + ks*32 + g*8);

  f32x4 s[2][8] = {};
#pragma unroll
  for (int ks = 0; ks < 4; ++ks)
#pragma unroll
    for (int b = 0; b < 8; ++b){
      const bf16x8 kf = *(const bf16x8*)(Kb + (size_t)(w*128 + b*16 + c)*DHD + ks*32 + g*8);
      s[0][b] = __builtin_amdgcn_mfma_f32_16x16x32_bf16(qf[0][ks], kf, s[0][b], 0,0,0);
      s[1][b] = __builtin_amdgcn_mfma_f32_16x16x32_bf16(qf[1][ks], kf, s[1][b], 0,0,0);
    }

  float mx[2][4], sm[2][4], inv[2][4];
#pragma unroll
  for (int a = 0; a < 2; ++a)
#pragma unroll
    for (int rr = 0; rr < 4; ++rr){
      float m = s[a][0][rr];
#pragma unroll
      for (int b = 1; b < 8; ++b) m = fmaxf(m, s[a][b][rr]);
#pragma unroll
      for (int off = 1; off < 16; off <<= 1) m = fmaxf(m, __shfl_xor(m, off));
      mx[a][rr] = m;
    }
  if (c == 0)
#pragma unroll
    for (int a = 0; a < 2; ++a)
#pragma unroll
      for (int rr = 0; rr < 4; ++rr) redm[w][a*16 + 4*g + rr] = mx[a][rr];
  __syncthreads();
#pragma unroll
  for (int a = 0; a < 2; ++a)
#pragma unroll
    for (int rr = 0; rr < 4; ++rr){
      const int lr = a*16 + 4*g + rr;
      mx[a][rr] = fmaxf(fmaxf(redm[0][lr], redm[1][lr]), fmaxf(redm[2][lr], redm[3][lr]));
      sm[a][rr] = 0.f;
    }
#pragma unroll
  for (int a = 0; a < 2; ++a)
#pragma unroll
    for (int b = 0; b < 8; ++b)
#pragma unroll
      for (int rr = 0; rr < 4; ++rr){
        const float p = __expf(s[a][b][rr] - mx[a][rr]);
        s[a][b][rr] = p;
        sm[a][rr] += p;
      }
#pragma unroll
  for (int a = 0; a < 2; ++a)
#pragma unroll
    for (int rr = 0; rr < 4; ++rr){
#pragma unroll
      for (int off = 1; off < 16; off <<= 1) sm[a][rr] += __shfl_xor(sm[a][rr], off);
    }
  if (c == 0)
#pragma unroll
    for (int a = 0; a < 2; ++a)
#pragma unroll
      for (int rr = 0; rr < 4; ++rr) reds[w][a*16 + 4*g + rr] = sm[a][rr];
  __syncthreads();
#pragma unroll
  for (int a = 0; a < 2; ++a)
#pragma unroll
    for (int rr = 0; rr < 4; ++rr){
      const int lr = a*16 + 4*g + rr;
      inv[a][rr] = 1.0f / (reds[0][lr] + reds[1][lr] + reds[2][lr] + reds[3][lr]);
    }

#pragma unroll
  for (int a = 0; a < 2; ++a)
#pragma unroll
    for (int b = 0; b < 8; ++b)
#pragma unroll
      for (int rr = 0; rr < 4; ++rr){
        const int lr  = a*16 + 4*g + rr;
        const int key = w*128 + b*16 + c;
        const int slot = (key >> 3) ^ (lr & 7);
        Pl[lr*512 + slot*8 + (key & 7)] = (bf16_t)(s[a][b][rr] * inv[a][rr]);
      }
  __syncthreads();

  f32x4 o[2][2] = {};
  const int dw = w * 32;
#pragma unroll
  for (int kst = 0; kst < 16; ++kst){
    bf16x8 pa2[2];
#pragma unroll
    for (int a = 0; a < 2; ++a){
      const int r = a*16 + c;
      const int slot = (kst*4 + g) ^ (r & 7);
      pa2[a] = *(const bf16x8*)&Pl[r*512 + slot*8];
    }
#pragma unroll
    for (int db = 0; db < 2; ++db){
      const bf16x8 vf = *(const bf16x8*)(Vb + (size_t)(dw + db*16 + c)*SEQL + kst*32 + g*8);
      o[0][db] = __builtin_amdgcn_mfma_f32_16x16x32_bf16(pa2[0], vf, o[0][db], 0,0,0);
      o[1][db] = __builtin_amdgcn_mfma_f32_16x16x32_bf16(pa2[1], vf, o[1][db], 0,0,0);
    }
  }
#pragma unroll
  for (int a = 0; a < 2; ++a)
#pragma unroll
    for (int db = 0; db < 2; ++db)
#pragma unroll
      for (int rr = 0; rr < 4; ++rr){
        const int row  = rb + a*16 + 4*g + rr;
        const int col2 = h*DHD + dw + db*16 + c;
        Aout[(size_t)row*DM + col2] = (bf16_t)o[a][db][rr];
      }
}

// ---------------------------------------------------------------------------
// Row LayerNorm over 2048. WB=1 additionally writes bf16 copy.
template<int WB>
__global__ __launch_bounds__(256)
void ln_kernel(const float* __restrict__ Y, const float* __restrict__ gam,
               const float* __restrict__ bet, float* __restrict__ outF,
               bf16_t* __restrict__ outB)
{
  const int row = blockIdx.x, tid = threadIdx.x;
  const float* x = Y + (size_t)row * DM;
  const float4 v0 = *(const float4*)(x + tid*8);
  const float4 v1 = *(const float4*)(x + tid*8 + 4);
  float s = v0.x+v0.y+v0.z+v0.w + v1.x+v1.y+v1.z+v1.w;
  float q = v0.x*v0.x+v0.y*v0.y+v0.z*v0.z+v0.w*v0.w
          + v1.x*v1.x+v1.y*v1.y+v1.z*v1.z+v1.w*v1.w;
#pragma unroll
  for (int off = 32; off >= 1; off >>= 1){ s += __shfl_xor(s, off); q += __shfl_xor(q, off); }
  __shared__ float rs[4], rq[4];
  const int w = tid >> 6;
  if ((tid & 63) == 0){ rs[w] = s; rq[w] = q; }
  __syncthreads();
  s = rs[0]+rs[1]+rs[2]+rs[3];
  q = rq[0]+rq[1]+rq[2]+rq[3];
  const float mu  = s * (1.0f/2048.0f);
  const float var = q * (1.0f/2048.0f) - mu*mu;
  const float rstd = rsqrtf(var + 1e-5f);
  const float4 g0 = *(const float4*)(gam + tid*8);
  const float4 g1 = *(const float4*)(gam + tid*8 + 4);
  const float4 b0 = *(const float4*)(bet + tid*8);
  const float4 b1 = *(const float4*)(bet + tid*8 + 4);
  float4 o0, o1;
  o0.x = (v0.x-mu)*rstd*g0.x + b0.x;  o0.y = (v0.y-mu)*rstd*g0.y + b0.y;
  o0.z = (v0.z-mu)*rstd*g0.z + b0.z;  o0.w = (v0.w-mu)*rstd*g0.w + b0.w;
  o1.x = (v1.x-mu)*rstd*g1.x + b1.x;  o1.y = (v1.y-mu)*rstd*g1.y + b1.y;
  o1.z = (v1.z-mu)*rstd*g1.z + b1.z;  o1.w = (v1.w-mu)*rstd*g1.w + b1.w;
  *(float4*)(outF + (size_t)row*DM + tid*8)     = o0;
  *(float4*)(outF + (size_t)row*DM + tid*8 + 4) = o1;
  if constexpr (WB){
    uint4 ob;
    ob.x = pack2(o0.x, o0.y); ob.y = pack2(o0.z, o0.w);
    ob.z = pack2(o1.x, o1.y); ob.w = pack2(o1.z, o1.w);
    *(uint4*)&outB[(size_t)row*DM + tid*8] = ob;
  }
}

// ---------------------------------------------------------------------------
extern "C" void kernel_launch(void* const* d_in, const int* in_sizes, int n_in,
                              void* d_out, int out_size, void* d_ws, size_t ws_size,
                              hipStream_t stream)
{
  const float* seq   = (const float*)d_in[0];
  const float* emb_W = (const float*)d_in[1];
  const float* emb_b = (const float*)d_in[2];
  const float* Wq = (const float*)d_in[3];  const float* bq = (const float*)d_in[4];
  const float* Wk = (const float*)d_in[5];  const float* bk = (const float*)d_in[6];
  const float* Wv = (const float*)d_in[7];  const float* bv = (const float*)d_in[8];
  const float* Wo = (const float*)d_in[9];  const float* bo = (const float*)d_in[10];
  const float* ln_g = (const float*)d_in[11]; const float* ln_b = (const float*)d_in[12];
  const float* W1 = (const float*)d_in[13]; const float* b1 = (const float*)d_in[14];
  const float* W2 = (const float*)d_in[15]; const float* b2 = (const float*)d_in[16];

  char* ws = (char*)d_ws;
  size_t off = 0;
  auto take = [&](size_t bytes) -> void* {
    void* p = ws + off;
    off += (bytes + 255) & ~(size_t)255;
    return p;
  };
  bf16_t* embT  = (bf16_t*)take((size_t)DM*DM*2);
  bf16_t* WqkvT = (bf16_t*)take((size_t)3*DM*DM*2);
  bf16_t* WoTp  = (bf16_t*)take((size_t)DM*DM*2);
  bf16_t* W1T   = (bf16_t*)take((size_t)FFH*DM*2);
  bf16_t* W2T   = (bf16_t*)take((size_t)DM*FFH*2);
  bf16_t* seqB  = (bf16_t*)take((size_t)SEQL*DM*2);
  float*  X     = (float*) take((size_t)SEQL*DM*4);
  bf16_t* XB    = (bf16_t*)take((size_t)SEQL*DM*2);
  bf16_t* Qf    = (bf16_t*)take((size_t)SEQL*DM*2);
  bf16_t* Kf    = (bf16_t*)take((size_t)SEQL*DM*2);
  bf16_t* Qhd   = (bf16_t*)take((size_t)SEQL*DM*2);
  bf16_t* Khd   = (bf16_t*)take((size_t)SEQL*DM*2);
  bf16_t* Vt    = (bf16_t*)take((size_t)SEQL*DM*2);
  bf16_t* Afl   = (bf16_t*)take((size_t)SEQL*DM*2);
  float*  Y     = (float*) take((size_t)SEQL*DM*4);
  float*  Xa    = (float*) take((size_t)SEQL*DM*4);
  bf16_t* XaB   = (bf16_t*)take((size_t)SEQL*DM*2);
  bf16_t* Hb    = (bf16_t*)take((size_t)SEQL*FFH*2);
  (void)ws_size; (void)in_sizes; (void)n_in; (void)out_size;

  // prep: sequence convert + all weight transposes in one launch
  cvt_bf16<<<dim3(SEQL*DM/1024), 256, 0, stream>>>(seq, seqB);
  TArgs ta;
  ta.e[0] = { emb_W, embT,                DM,  DM,  32,     0, 0 };
  ta.e[1] = { Wq,    WqkvT,               DM,  DM,  32,  1024, 0 };
  ta.e[2] = { Wk,    WqkvT + (size_t)DM*DM,   DM,  DM,  32,  2048, 0 };
  ta.e[3] = { Wv,    WqkvT + (size_t)2*DM*DM, DM,  DM,  32,  3072, 0 };
  ta.e[4] = { Wo,    WoTp,                DM,  DM,  32,  4096, 1 };
  ta.e[5] = { W1,    W1T,                 DM,  FFH, 32,  5120, 0 };
  ta.e[6] = { W2,    W2T,                 FFH, DM, 128,  9216, 0 };
  prep_transpose<<<dim3(13312), 256, 0, stream>>>(ta);

  // embedding + positional encoding
  gemm128<E_X><<<dim3(16,4), 256, 0, stream>>>(seqB, embT, emb_b, nullptr, nullptr,
                                               nullptr, X, XB, nullptr, nullptr, DM, DM);
  // fused QKV
  gemm128<E_QKV><<<dim3(48,4), 256, 0, stream>>>(XB, WqkvT, bq, bk, bv,
                                                 nullptr, nullptr, Qf, Kf, Vt, 3*DM, DM);
  permute_qk<<<dim3(SEQL,2), 256, 0, stream>>>(Qf, Kf, Qhd, Khd);
  attn_kernel<<<dim3(16,16), 256, 0, stream>>>(Qhd, Khd, Vt, Afl);
  // output proj + residual, LN1
  gemm128<E_AO><<<dim3(16,4), 256, 0, stream>>>(Afl, WoTp, bo, nullptr, nullptr,
                                                X, Y, nullptr, nullptr, nullptr, DM, DM);
  ln_kernel<1><<<SEQL, 256, 0, stream>>>(Y, ln_g, ln_b, Xa, XaB);
  // FFN
  gemm128<E_FFN1><<<dim3(64,4), 256, 0, stream>>>(XaB, W1T, b1, nullptr, nullptr,
                                                  nullptr, nullptr, Hb, nullptr, nullptr, FFH, DM);
  gemm128<E_FFN2><<<dim3(16,4), 256, 0, stream>>>(Hb, W2T, b2, nullptr, nullptr,
                                                  Xa, Y, nullptr, nullptr, nullptr, DM, FFH);
  ln_kernel<0><<<SEQL, 256, 0, stream>>>(Y, ln_g, ln_b, (float*)d_out, nullptr);
}

// Round 3
// 246.129 us; speedup vs baseline: 1.6780x; 1.6780x over previous
//
#include <hip/hip_runtime.h>
#include <hip/hip_bf16.h>

// ---------------------------------------------------------------------------
// TransformerEncoder forward on MI355X (gfx950). Round 2:
//   - GEMM re-shaped for M=512: 64x128 tile, BK=32, 4 waves, split-K for the
//     N=2048 GEMMs (512 blocks each; round 1's 64-block grid was the killer)
//   - split-K partials reduced by fused kernels (posenc / residual+LayerNorm)
//   - Q/K head-permute folded into weight prep; permute_qk kernel deleted
// ---------------------------------------------------------------------------

typedef __bf16 bf16_t;
typedef __bf16 bf16x8 __attribute__((ext_vector_type(8)));
typedef float  f32x4  __attribute__((ext_vector_type(4)));

#define SEQL 512
#define DM   2048
#define FFH  8192
#define NH   16
#define DHD  128
#define PST  ((size_t)SEQL*DM)   // partial-slice stride

__device__ __forceinline__ unsigned short bfbits(float f){
  bf16_t h = (bf16_t)f;
  return __builtin_bit_cast(unsigned short, h);
}
__device__ __forceinline__ unsigned int pack2(float a, float b){
  return (unsigned int)bfbits(a) | ((unsigned int)bfbits(b) << 16);
}

__device__ __forceinline__ void gll16(const bf16_t* g, bf16_t* l){
  __builtin_amdgcn_global_load_lds(
      (const __attribute__((address_space(1))) void*)g,
      (__attribute__((address_space(3))) void*)l, 16, 0, 0);
}

// ---------------------------------------------------------------------------
// fp32 -> bf16 elementwise convert (for `sequence`)
__global__ __launch_bounds__(256)
void cvt_bf16(const float* __restrict__ in, bf16_t* __restrict__ out){
  const int i = (blockIdx.x * 256 + threadIdx.x) * 4;
  const float4 v = *(const float4*)(in + i);
  ushort4 o;
  o.x = bfbits(v.x); o.y = bfbits(v.y); o.z = bfbits(v.z); o.w = bfbits(v.w);
  *(ushort4*)(out + i) = o;
}

// ---------------------------------------------------------------------------
// Batched transpose+convert: out[n][k] = in[k][n] as bf16 ([K][N] -> [N][K]).
// perm  = 1 (Wo):     source row k' reads in[16*(k'&127)+(k'>>7)][*]
// wperm = 1 (Wq/Wk):  dest row n  writes to row (n&15)*128 + (n>>4)
struct TEnt { const float* src; bf16_t* dst; int inR, inC, tilesX, tileBase, perm, wperm; };
struct TArgs { TEnt e[7]; };

__global__ __launch_bounds__(256)
void prep_transpose(TArgs args){
  __shared__ bf16_t t[64*65];
  const int b = blockIdx.x;
  int i = 0;
#pragma unroll
  for (int j = 1; j < 7; ++j) if (b >= args.e[j].tileBase) i = j;
  const TEnt E = args.e[i];
  const int tloc = b - E.tileBase;
  const int tx = tloc % E.tilesX, ty = tloc / E.tilesX;
  const int C0 = tx * 64, R0 = ty * 64;
  const int tid = threadIdx.x;
#pragma unroll
  for (int it = 0; it < 4; ++it){
    const int ii = it*16 + (tid >> 4);
    const int j0 = (tid & 15) * 4;
    const int cc = C0 + ii;
    const int srow = E.perm ? (((cc & 127) << 4) + (cc >> 7)) : cc;
    const float4 v = *(const float4*)(E.src + (size_t)srow * E.inC + R0 + j0);
    t[(j0+0)*65 + ii] = (bf16_t)v.x;
    t[(j0+1)*65 + ii] = (bf16_t)v.y;
    t[(j0+2)*65 + ii] = (bf16_t)v.z;
    t[(j0+3)*65 + ii] = (bf16_t)v.w;
  }
  __syncthreads();
#pragma unroll
  for (int it = 0; it < 2; ++it){
    const int r  = it*32 + (tid >> 3);
    const int c0 = (tid & 7) * 8;
    unsigned short us[8];
#pragma unroll
    for (int u = 0; u < 8; ++u) us[u] = __builtin_bit_cast(unsigned short, t[r*65 + c0 + u]);
    uint4 o;
    o.x = (unsigned)us[0] | ((unsigned)us[1] << 16);
    o.y = (unsigned)us[2] | ((unsigned)us[3] << 16);
    o.z = (unsigned)us[4] | ((unsigned)us[5] << 16);
    o.w = (unsigned)us[6] | ((unsigned)us[7] << 16);
    const int orow = R0 + r;
    const int drow = E.wperm ? (((orow & 15) << 7) + (orow >> 4)) : orow;
    *(uint4*)(E.dst + (size_t)drow * E.inR + C0 + c0) = o;
  }
}

// ---------------------------------------------------------------------------
// GEMM: C[512][N] = A[512][K] @ BT[N][K]^T (+ epilogue). 64x128 tile, BK=32,
// 256 threads, 4 waves (wave w -> 32x64 sub-tile, 2x4 16x16x32 frags).
// Split-K via blockIdx.z (Kc columns per slice) for E_PART.
constexpr int E_PART = 0;  // fp32 partial (no bias) -> outF + z*PST
constexpr int E_QKV  = 1;  // [0,2k)->Qf(head-major), [2k,4k)->Kf, rest->Vt[h][d][key]
constexpr int E_FFN1 = 2;  // bias + gelu -> bf16 [512][FFH]

template<int EPI>
__global__ __launch_bounds__(256, 4)
void gemm64(const bf16_t* __restrict__ A, const bf16_t* __restrict__ BT,
            const float* __restrict__ b0p, const float* __restrict__ b1p,
            const float* __restrict__ b2p,
            float* __restrict__ outF, bf16_t* __restrict__ o0,
            bf16_t* __restrict__ o1, bf16_t* __restrict__ o2,
            int N, int K, int Kc)
{
  __shared__ bf16_t sA[2][64*32];
  __shared__ bf16_t sB[2][128*32];
  const int tid  = threadIdx.x;
  const int lane = tid & 63, w = tid >> 6;
  const int wr = w >> 1, wc = w & 1;
  const int c = lane & 15, g = lane >> 4;
  const int m0 = blockIdx.y * 64, n0 = blockIdx.x * 128;
  const int k0 = blockIdx.z * Kc;

  // staging sources (pre-swizzled 16B slot within each 64B k-row)
  const int sr = tid >> 2, ss = tid & 3;
  const int scol = ((ss ^ ((sr >> 1) & 3)) << 3);
  const bf16_t* Asrc  = A  + (size_t)(m0 + sr) * K + k0 + scol;
  const bf16_t* Bsrc0 = BT + (size_t)(n0 + sr) * K + k0 + scol;
  const bf16_t* Bsrc1 = BT + (size_t)(n0 + 64 + sr) * K + k0 + scol;

  // fragment read offsets (elements into [rows][32] buffers)
  int raA[2], raB[4];
#pragma unroll
  for (int m = 0; m < 2; ++m){
    const int r = wr*32 + m*16 + c;
    raA[m] = r*32 + ((g ^ ((r >> 1) & 3)) << 3);
  }
#pragma unroll
  for (int n = 0; n < 4; ++n){
    const int r = wc*64 + n*16 + c;
    raB[n] = r*32 + ((g ^ ((r >> 1) & 3)) << 3);
  }

#define STAGE(buf, kt) {                                      \
    gll16(Asrc  + (size_t)(kt)*32, &sA[buf][tid*8]);          \
    gll16(Bsrc0 + (size_t)(kt)*32, &sB[buf][tid*8]);          \
    gll16(Bsrc1 + (size_t)(kt)*32, &sB[buf][2048 + tid*8]);   }

  f32x4 acc[2][4] = {};
  const int nk = Kc >> 5;

  STAGE(0, 0);
  asm volatile("s_waitcnt vmcnt(0)" ::: "memory");
  __builtin_amdgcn_s_barrier();
  __builtin_amdgcn_sched_barrier(0);

  int buf = 0;
  for (int kt = 0; kt < nk; ++kt){
    if (kt + 1 < nk) STAGE(buf ^ 1, kt + 1);
    bf16x8 af[2], bq[4];
#pragma unroll
    for (int m = 0; m < 2; ++m) af[m] = *(const bf16x8*)&sA[buf][raA[m]];
#pragma unroll
    for (int n = 0; n < 4; ++n) bq[n] = *(const bf16x8*)&sB[buf][raB[n]];
#pragma unroll
    for (int m = 0; m < 2; ++m)
#pragma unroll
      for (int n = 0; n < 4; ++n)
        acc[m][n] = __builtin_amdgcn_mfma_f32_16x16x32_bf16(af[m], bq[n], acc[m][n], 0,0,0);
    asm volatile("s_waitcnt vmcnt(0)" ::: "memory");
    __builtin_amdgcn_s_barrier();
    __builtin_amdgcn_sched_barrier(0);
    buf ^= 1;
  }
#undef STAGE

  // epilogue: row = m0 + wr*32 + m*16 + 4g + rr, col = n0 + wc*64 + n*16 + c
#pragma unroll
  for (int n = 0; n < 4; ++n){
    const int col = n0 + wc*64 + n*16 + c;
#pragma unroll
    for (int m = 0; m < 2; ++m){
      const int row0 = m0 + wr*32 + m*16 + 4*g;
      const f32x4 a4 = acc[m][n];
      if constexpr (EPI == E_PART){
        float* dst = outF + (size_t)blockIdx.z * PST;
#pragma unroll
        for (int rr = 0; rr < 4; ++rr)
          dst[(size_t)(row0+rr)*N + col] = a4[rr];
      } else if constexpr (EPI == E_QKV){
        if (col < DM){            // Q, head-major cols; bias index remapped
          const float bv = b0p[16*(col & 127) + (col >> 7)];
#pragma unroll
          for (int rr = 0; rr < 4; ++rr)
            o0[(size_t)(row0+rr)*DM + col] = (bf16_t)(a4[rr] + bv);
        } else if (col < 2*DM){   // K, head-major
          const int cc = col - DM;
          const float bv = b1p[16*(cc & 127) + (cc >> 7)];
#pragma unroll
          for (int rr = 0; rr < 4; ++rr)
            o1[(size_t)(row0+rr)*DM + cc] = (bf16_t)(a4[rr] + bv);
        } else {                  // V -> Vt[h][d][key]
          const int cc = col - 2*DM;
          const float bv = b2p[cc];
          const int hh = cc & 15, dd = cc >> 4;
          unsigned short us[4];
#pragma unroll
          for (int rr = 0; rr < 4; ++rr) us[rr] = bfbits(a4[rr] + bv);
          *(ushort4*)&o2[(size_t)(hh*DHD + dd)*SEQL + row0] =
              make_ushort4(us[0], us[1], us[2], us[3]);
        }
      } else if constexpr (EPI == E_FFN1){
        const float bv = b0p[col];
#pragma unroll
        for (int rr = 0; rr < 4; ++rr){
          const float v = a4[rr] + bv;
          const float z = v * (v*v*0.044715f + 1.0f) * 1.5957691216f;
          const float gg = v / (1.0f + __expf(-z));
          o0[(size_t)(row0+rr)*FFH + col] = (bf16_t)gg;
        }
      }
    }
  }
}

// ---------------------------------------------------------------------------
// reduce 4 split-K partials + bias + positional encoding -> X fp32 + XB bf16
__global__ __launch_bounds__(256)
void reduce_pos(const float* __restrict__ P, const float* __restrict__ bias,
                float* __restrict__ X, bf16_t* __restrict__ XB)
{
  const int row = blockIdx.x, c0 = threadIdx.x * 8;
  const size_t base = (size_t)row * DM + c0;
  float y[8];
#pragma unroll
  for (int j = 0; j < 8; ++j) y[j] = bias[c0 + j];
#pragma unroll
  for (int s = 0; s < 4; ++s){
    const float4 v0 = *(const float4*)(P + s*PST + base);
    const float4 v1 = *(const float4*)(P + s*PST + base + 4);
    y[0]+=v0.x; y[1]+=v0.y; y[2]+=v0.z; y[3]+=v0.w;
    y[4]+=v1.x; y[5]+=v1.y; y[6]+=v1.z; y[7]+=v1.w;
  }
#pragma unroll
  for (int j = 0; j < 8; ++j){
    const int col = c0 + j;
    const float fr  = 1e-4f * __expf(-(float)(col >> 1) * (1.0f/1024.0f));
    const float ang = (float)row * fr;
    y[j] += (col & 1) ? __cosf(ang) : __sinf(ang);
  }
  *(float4*)(X + base)     = make_float4(y[0], y[1], y[2], y[3]);
  *(float4*)(X + base + 4) = make_float4(y[4], y[5], y[6], y[7]);
  uint4 ob;
  ob.x = pack2(y[0], y[1]); ob.y = pack2(y[2], y[3]);
  ob.z = pack2(y[4], y[5]); ob.w = pack2(y[6], y[7]);
  *(uint4*)&XB[base] = ob;
}

// ---------------------------------------------------------------------------
// reduce S split-K partials + bias + residual, then row-LayerNorm(2048).
// WB=1 additionally writes bf16 copy.
template<int S, int WB>
__global__ __launch_bounds__(256)
void reduce_ln(const float* __restrict__ P, const float* __restrict__ bias,
               const float* __restrict__ resid, const float* __restrict__ gam,
               const float* __restrict__ bet, float* __restrict__ outF,
               bf16_t* __restrict__ outB)
{
  const int row = blockIdx.x, tid = threadIdx.x, c0 = tid * 8;
  const size_t base = (size_t)row * DM + c0;
  float y[8];
  {
    const float4 r0 = *(const float4*)(resid + base);
    const float4 r1 = *(const float4*)(resid + base + 4);
    y[0]=r0.x; y[1]=r0.y; y[2]=r0.z; y[3]=r0.w;
    y[4]=r1.x; y[5]=r1.y; y[6]=r1.z; y[7]=r1.w;
  }
#pragma unroll
  for (int j = 0; j < 8; ++j) y[j] += bias[c0 + j];
#pragma unroll
  for (int s = 0; s < S; ++s){
    const float4 v0 = *(const float4*)(P + s*PST + base);
    const float4 v1 = *(const float4*)(P + s*PST + base + 4);
    y[0]+=v0.x; y[1]+=v0.y; y[2]+=v0.z; y[3]+=v0.w;
    y[4]+=v1.x; y[5]+=v1.y; y[6]+=v1.z; y[7]+=v1.w;
  }
  float sm = 0.f, qs = 0.f;
#pragma unroll
  for (int j = 0; j < 8; ++j){ sm += y[j]; qs += y[j]*y[j]; }
#pragma unroll
  for (int off = 32; off >= 1; off >>= 1){
    sm += __shfl_xor(sm, off); qs += __shfl_xor(qs, off);
  }
  __shared__ float rs[4], rq[4];
  const int w = tid >> 6;
  if ((tid & 63) == 0){ rs[w] = sm; rq[w] = qs; }
  __syncthreads();
  sm = rs[0]+rs[1]+rs[2]+rs[3];
  qs = rq[0]+rq[1]+rq[2]+rq[3];
  const float mu   = sm * (1.0f/2048.0f);
  const float var  = qs * (1.0f/2048.0f) - mu*mu;
  const float rstd = rsqrtf(var + 1e-5f);
  const float4 g0 = *(const float4*)(gam + c0);
  const float4 g1 = *(const float4*)(gam + c0 + 4);
  const float4 b0 = *(const float4*)(bet + c0);
  const float4 b1 = *(const float4*)(bet + c0 + 4);
  float o[8];
  o[0] = (y[0]-mu)*rstd*g0.x + b0.x;  o[1] = (y[1]-mu)*rstd*g0.y + b0.y;
  o[2] = (y[2]-mu)*rstd*g0.z + b0.z;  o[3] = (y[3]-mu)*rstd*g0.w + b0.w;
  o[4] = (y[4]-mu)*rstd*g1.x + b1.x;  o[5] = (y[5]-mu)*rstd*g1.y + b1.y;
  o[6] = (y[6]-mu)*rstd*g1.z + b1.z;  o[7] = (y[7]-mu)*rstd*g1.w + b1.w;
  *(float4*)(outF + base)     = make_float4(o[0], o[1], o[2], o[3]);
  *(float4*)(outF + base + 4) = make_float4(o[4], o[5], o[6], o[7]);
  if constexpr (WB){
    uint4 ob;
    ob.x = pack2(o[0], o[1]); ob.y = pack2(o[2], o[3]);
    ob.z = pack2(o[4], o[5]); ob.w = pack2(o[6], o[7]);
    *(uint4*)&outB[base] = ob;
  }
}

// ---------------------------------------------------------------------------
// Attention: one block per (32 q-rows, head). Full softmax over 512 keys.
// Qf/Kf: [row][h*128+d] bf16 (head-major), Vt: [h][d][key], Aout: [row][h*128+d]
__global__ __launch_bounds__(256)
void attn_kernel(const bf16_t* __restrict__ Qf, const bf16_t* __restrict__ Kf,
                 const bf16_t* __restrict__ Vt, bf16_t* __restrict__ Aout)
{
  __shared__ bf16_t Pl[32*512];
  __shared__ float redm[4][32];
  __shared__ float reds[4][32];
  const int tid = threadIdx.x;
  const int lane = tid & 63, w = tid >> 6;
  const int c = lane & 15, g = lane >> 4;
  const int h = blockIdx.y;
  const int rb = blockIdx.x * 32;
  const bf16_t* Qb = Qf + h*DHD;
  const bf16_t* Kb = Kf + h*DHD;
  const bf16_t* Vb = Vt + (size_t)h * (SEQL*DHD);

  bf16x8 qf[2][4];
#pragma unroll
  for (int a = 0; a < 2; ++a)
#pragma unroll
    for (int ks = 0; ks < 4; ++ks)
      qf[a][ks] = *(const bf16x8*)(Qb + (size_t)(rb + a*16 + c)*DM + ks*32 + g*8);

  f32x4 s[2][8] = {};
#pragma unroll
  for (int ks = 0; ks < 4; ++ks)
#pragma unroll
    for (int b = 0; b < 8; ++b){
      const bf16x8 kf = *(const bf16x8*)(Kb + (size_t)(w*128 + b*16 + c)*DM + ks*32 + g*8);
      s[0][b] = __builtin_amdgcn_mfma_f32_16x16x32_bf16(qf[0][ks], kf, s[0][b], 0,0,0);
      s[1][b] = __builtin_amdgcn_mfma_f32_16x16x32_bf16(qf[1][ks], kf, s[1][b], 0,0,0);
    }
  // 1/sqrt(2048) score scale (folded out of Q)
#pragma unroll
  for (int a = 0; a < 2; ++a)
#pragma unroll
    for (int b = 0; b < 8; ++b)
#pragma unroll
      for (int rr = 0; rr < 4; ++rr) s[a][b][rr] *= 0.022097086912079612f;

  float mx[2][4], sm[2][4], inv[2][4];
#pragma unroll
  for (int a = 0; a < 2; ++a)
#pragma unroll
    for (int rr = 0; rr < 4; ++rr){
      float m = s[a][0][rr];
#pragma unroll
      for (int b = 1; b < 8; ++b) m = fmaxf(m, s[a][b][rr]);
#pragma unroll
      for (int off = 1; off < 16; off <<= 1) m = fmaxf(m, __shfl_xor(m, off));
      mx[a][rr] = m;
    }
  if (c == 0)
#pragma unroll
    for (int a = 0; a < 2; ++a)
#pragma unroll
      for (int rr = 0; rr < 4; ++rr) redm[w][a*16 + 4*g + rr] = mx[a][rr];
  __syncthreads();
#pragma unroll
  for (int a = 0; a < 2; ++a)
#pragma unroll
    for (int rr = 0; rr < 4; ++rr){
      const int lr = a*16 + 4*g + rr;
      mx[a][rr] = fmaxf(fmaxf(redm[0][lr], redm[1][lr]), fmaxf(redm[2][lr], redm[3][lr]));
      sm[a][rr] = 0.f;
    }
#pragma unroll
  for (int a = 0; a < 2; ++a)
#pragma unroll
    for (int b = 0; b < 8; ++b)
#pragma unroll
      for (int rr = 0; rr < 4; ++rr){
        const float p = __expf(s[a][b][rr] - mx[a][rr]);
        s[a][b][rr] = p;
        sm[a][rr] += p;
      }
#pragma unroll
  for (int a = 0; a < 2; ++a)
#pragma unroll
    for (int rr = 0; rr < 4; ++rr){
#pragma unroll
      for (int off = 1; off < 16; off <<= 1) sm[a][rr] += __shfl_xor(sm[a][rr], off);
    }
  if (c == 0)
#pragma unroll
    for (int a = 0; a < 2; ++a)
#pragma unroll
      for (int rr = 0; rr < 4; ++rr) reds[w][a*16 + 4*g + rr] = sm[a][rr];
  __syncthreads();
#pragma unroll
  for (int a = 0; a < 2; ++a)
#pragma unroll
    for (int rr = 0; rr < 4; ++rr){
      const int lr = a*16 + 4*g + rr;
      inv[a][rr] = 1.0f / (reds[0][lr] + reds[1][lr] + reds[2][lr] + reds[3][lr]);
    }

#pragma unroll
  for (int a = 0; a < 2; ++a)
#pragma unroll
    for (int b = 0; b < 8; ++b)
#pragma unroll
      for (int rr = 0; rr < 4; ++rr){
        const int lr  = a*16 + 4*g + rr;
        const int key = w*128 + b*16 + c;
        const int slot = (key >> 3) ^ (lr & 7);
        Pl[lr*512 + slot*8 + (key & 7)] = (bf16_t)(s[a][b][rr] * inv[a][rr]);
      }
  __syncthreads();

  f32x4 o[2][2] = {};
  const int dw = w * 32;
#pragma unroll
  for (int kst = 0; kst < 16; ++kst){
    bf16x8 pa2[2];
#pragma unroll
    for (int a = 0; a < 2; ++a){
      const int r = a*16 + c;
      const int slot = (kst*4 + g) ^ (r & 7);
      pa2[a] = *(const bf16x8*)&Pl[r*512 + slot*8];
    }
#pragma unroll
    for (int db = 0; db < 2; ++db){
      const bf16x8 vf = *(const bf16x8*)(Vb + (size_t)(dw + db*16 + c)*SEQL + kst*32 + g*8);
      o[0][db] = __builtin_amdgcn_mfma_f32_16x16x32_bf16(pa2[0], vf, o[0][db], 0,0,0);
      o[1][db] = __builtin_amdgcn_mfma_f32_16x16x32_bf16(pa2[1], vf, o[1][db], 0,0,0);
    }
  }
#pragma unroll
  for (int a = 0; a < 2; ++a)
#pragma unroll
    for (int db = 0; db < 2; ++db)
#pragma unroll
      for (int rr = 0; rr < 4; ++rr){
        const int row  = rb + a*16 + 4*g + rr;
        const int col2 = h*DHD + dw + db*16 + c;
        Aout[(size_t)row*DM + col2] = (bf16_t)o[a][db][rr];
      }
}

// ---------------------------------------------------------------------------
extern "C" void kernel_launch(void* const* d_in, const int* in_sizes, int n_in,
                              void* d_out, int out_size, void* d_ws, size_t ws_size,
                              hipStream_t stream)
{
  const float* seq   = (const float*)d_in[0];
  const float* emb_W = (const float*)d_in[1];
  const float* emb_b = (const float*)d_in[2];
  const float* Wq = (const float*)d_in[3];  const float* bq = (const float*)d_in[4];
  const float* Wk = (const float*)d_in[5];  const float* bk = (const float*)d_in[6];
  const float* Wv = (const float*)d_in[7];  const float* bv = (const float*)d_in[8];
  const float* Wo = (const float*)d_in[9];  const float* bo = (const float*)d_in[10];
  const float* ln_g = (const float*)d_in[11]; const float* ln_b = (const float*)d_in[12];
  const float* W1 = (const float*)d_in[13]; const float* b1 = (const float*)d_in[14];
  const float* W2 = (const float*)d_in[15]; const float* b2 = (const float*)d_in[16];

  char* ws = (char*)d_ws;
  size_t off = 0;
  auto take = [&](size_t bytes) -> void* {
    void* p = ws + off;
    off += (bytes + 255) & ~(size_t)255;
    return p;
  };
  bf16_t* embT  = (bf16_t*)take((size_t)DM*DM*2);
  bf16_t* WqkvT = (bf16_t*)take((size_t)3*DM*DM*2);   // Hb aliases this later
  bf16_t* WoTp  = (bf16_t*)take((size_t)DM*DM*2);
  bf16_t* W1T   = (bf16_t*)take((size_t)FFH*DM*2);
  bf16_t* W2T   = (bf16_t*)take((size_t)DM*FFH*2);
  bf16_t* seqB  = (bf16_t*)take((size_t)SEQL*DM*2);
  float*  X     = (float*) take((size_t)SEQL*DM*4);
  bf16_t* XB    = (bf16_t*)take((size_t)SEQL*DM*2);
  bf16_t* Qf    = (bf16_t*)take((size_t)SEQL*DM*2);
  bf16_t* Kf    = (bf16_t*)take((size_t)SEQL*DM*2);
  bf16_t* Vt    = (bf16_t*)take((size_t)SEQL*DM*2);
  bf16_t* Afl   = (bf16_t*)take((size_t)SEQL*DM*2);
  float*  Pp    = (float*) take((size_t)4*SEQL*DM*4); // split-K partials (16 MB)
  float*  Xa    = (float*) take((size_t)SEQL*DM*4);
  bf16_t* XaB   = (bf16_t*)take((size_t)SEQL*DM*2);
  bf16_t* Hb    = WqkvT;                              // [512][8192] bf16, aliased
  (void)ws_size; (void)in_sizes; (void)n_in; (void)out_size;

  // prep: sequence convert + all weight transposes in one launch
  cvt_bf16<<<dim3(SEQL*DM/1024), 256, 0, stream>>>(seq, seqB);
  TArgs ta;
  ta.e[0] = { emb_W, embT,                    DM,  DM,   32,    0, 0, 0 };
  ta.e[1] = { Wq,    WqkvT,                   DM,  DM,   32, 1024, 0, 1 };
  ta.e[2] = { Wk,    WqkvT + (size_t)DM*DM,   DM,  DM,   32, 2048, 0, 1 };
  ta.e[3] = { Wv,    WqkvT + (size_t)2*DM*DM, DM,  DM,   32, 3072, 0, 0 };
  ta.e[4] = { Wo,    WoTp,                    DM,  DM,   32, 4096, 1, 0 };
  ta.e[5] = { W1,    W1T,                     DM,  FFH,  32, 5120, 0, 0 };
  ta.e[6] = { W2,    W2T,                     FFH, DM,  128, 9216, 0, 0 };
  prep_transpose<<<dim3(13312), 256, 0, stream>>>(ta);

  // embedding (split-K x4) + posenc reduce
  gemm64<E_PART><<<dim3(16,8,4), 256, 0, stream>>>(seqB, embT, nullptr, nullptr, nullptr,
                                                   Pp, nullptr, nullptr, nullptr, DM, DM, 512);
  reduce_pos<<<SEQL, 256, 0, stream>>>(Pp, emb_b, X, XB);
  // fused QKV (N=6144, 384 blocks)
  gemm64<E_QKV><<<dim3(48,8,1), 256, 0, stream>>>(XB, WqkvT, bq, bk, bv,
                                                  nullptr, Qf, Kf, Vt, 3*DM, DM, DM);
  attn_kernel<<<dim3(16,16), 256, 0, stream>>>(Qf, Kf, Vt, Afl);
  // output projection (split-K x4) + residual + LN1
  gemm64<E_PART><<<dim3(16,8,4), 256, 0, stream>>>(Afl, WoTp, nullptr, nullptr, nullptr,
                                                   Pp, nullptr, nullptr, nullptr, DM, DM, 512);
  reduce_ln<4,1><<<SEQL, 256, 0, stream>>>(Pp, bo, X, ln_g, ln_b, Xa, XaB);
  // FFN1 (N=8192, 512 blocks)
  gemm64<E_FFN1><<<dim3(64,8,1), 256, 0, stream>>>(XaB, W1T, b1, nullptr, nullptr,
                                                   nullptr, Hb, nullptr, nullptr, FFH, DM, DM);
  // FFN2 (split-K x4, Kc=2048) + residual + LN2 -> out
  gemm64<E_PART><<<dim3(16,8,4), 256, 0, stream>>>(Hb, W2T, nullptr, nullptr, nullptr,
                                                   Pp, nullptr, nullptr, nullptr, DM, FFH, 2048);
  reduce_ln<4,0><<<SEQL, 256, 0, stream>>>(Pp, b2, Xa, ln_g, ln_b, (float*)d_out, nullptr);
}